// Round 7
// baseline (257.489 us; speedup 1.0000x reference)
//
#include <hip/hip_runtime.h>
#include <cstdint>
#include <cstddef>

#define NIMG 32
#define NCLS 81
#define NC1  80
#define NBOX 8732
#define CAP  65536
#define TOPK 400
#define MAXOUT 100
#define KW   7             // 400 bits -> 7 u64 words
#define COLCAP 2048
#define BDEC 256
#define CCH  27            // classes per LDS chunk (81 = 3*27)
#define NCHUNK 3

__device__ __forceinline__ unsigned int f2sort(float f) {
    unsigned int u = __float_as_uint(f);
    return (u & 0x80000000u) ? ~u : (u | 0x80000000u);
}

// ============ kernel 1: decode + chunked-LDS softmax + filter, 1 box/thread ============
__global__ __launch_bounds__(BDEC) void k_decode(const float* __restrict__ bboxes,
        const float* __restrict__ scores, const float* __restrict__ dbox,
        float4* __restrict__ oboxes, uint2* __restrict__ cand, int* __restrict__ cnt) {
    __shared__ float tile[CCH * BDEC];      // 27 KB
    int n = blockIdx.y;
    int b0 = blockIdx.x * BDEC;
    int tid = threadIdx.x;
    int lane = tid & 63;
    int b = b0 + tid;
    bool live = (b < NBOX);

    // ---- box decode ----
    bool go = false;
    float l = 0.f, tt = 0.f, rr = 0.f, bo = 0.f;
    if (live) {
        const float* bp = bboxes + (size_t)n * 4 * NBOX + b;
        float bx = bp[0], by = bp[NBOX], bw = bp[2 * NBOX], bh = bp[3 * NBOX];
        float4 d = reinterpret_cast<const float4*>(dbox)[b];
        float cx = 0.1f * bx * d.z + d.x;
        float cy = 0.1f * by * d.w + d.y;
        float ww = expf(0.2f * bw) * d.z;
        float hh = expf(0.2f * bh) * d.w;
        l = cx - 0.5f * ww;  tt = cy - 0.5f * hh;
        rr = cx + 0.5f * ww; bo = cy + 0.5f * hh;
        l = fminf(fmaxf(l, 0.f), 1.f);  tt = fminf(fmaxf(tt, 0.f), 1.f);
        rr = fminf(fmaxf(rr, 0.f), 1.f); bo = fminf(fmaxf(bo, 0.f), 1.f);
        const float MINS = 1.0f / 300.0f;
        go = (rr - l >= MINS) && (bo - tt >= MINS);
    }

    const size_t srow = (size_t)n * NCLS * NBOX;

    // ---- pass 1: per-box max over classes (chunked float4 staging) ----
    float m = -3.4e38f;
    #pragma unroll
    for (int k = 0; k < NCHUNK; ++k) {
        __syncthreads();
        #pragma unroll
        for (int t = 0; t < 7; ++t) {
            int idx = tid + t * BDEC;
            if (idx < CCH * (BDEC / 4)) {
                int c = idx >> 6;           // class within chunk (64 float4 per row)
                int q = idx & 63;           // float4 within row
                int cls = k * CCH + c;
                int bb = b0 + 4 * q;
                size_t g = srow + (size_t)cls * NBOX + bb;
                float4 v;
                if (bb + 3 < NBOX) v = *reinterpret_cast<const float4*>(scores + g);
                else {
                    v.x = (bb     < NBOX) ? scores[g]     : 0.f;
                    v.y = (bb + 1 < NBOX) ? scores[g + 1] : 0.f;
                    v.z = (bb + 2 < NBOX) ? scores[g + 2] : 0.f;
                    v.w = 0.f;
                }
                *reinterpret_cast<float4*>(&tile[c * BDEC + 4 * q]) = v;
            }
        }
        __syncthreads();
        #pragma unroll
        for (int c = 0; c < CCH; ++c) m = fmaxf(m, tile[c * BDEC + tid]);
    }

    // ---- pass 2: exp + exact serial-order sum, e[] register-resident ----
    float e[NCLS];
    float ss = 0.f;
    #pragma unroll
    for (int k = 0; k < NCHUNK; ++k) {
        __syncthreads();
        #pragma unroll
        for (int t = 0; t < 7; ++t) {
            int idx = tid + t * BDEC;
            if (idx < CCH * (BDEC / 4)) {
                int c = idx >> 6;
                int q = idx & 63;
                int cls = k * CCH + c;
                int bb = b0 + 4 * q;
                size_t g = srow + (size_t)cls * NBOX + bb;
                float4 v;
                if (bb + 3 < NBOX) v = *reinterpret_cast<const float4*>(scores + g);
                else {
                    v.x = (bb     < NBOX) ? scores[g]     : 0.f;
                    v.y = (bb + 1 < NBOX) ? scores[g + 1] : 0.f;
                    v.z = (bb + 2 < NBOX) ? scores[g + 2] : 0.f;
                    v.w = 0.f;
                }
                *reinterpret_cast<float4*>(&tile[c * BDEC + 4 * q]) = v;
            }
        }
        __syncthreads();
        #pragma unroll
        for (int c = 0; c < CCH; ++c) {
            float ev = expf(tile[c * BDEC + tid] - m);
            e[k * CCH + c] = ev;
            ss += ev;
        }
    }

    // ---- probabilities + filter (reference arithmetic: divide then compare) ----
    unsigned long long mlo = 0ull;   // classes 1..64
    unsigned int       mhi = 0u;     // classes 65..80
    #pragma unroll
    for (int c = 1; c < NCLS; ++c) {
        float p = e[c] / ss;
        e[c] = p;
        if (go && (p > 0.05f)) {
            if (c <= 64) mlo |= 1ull << (c - 1);
            else         mhi |= 1u << (c - 65);
        }
    }

    // ---- wave-aggregated reservation ----
    int nc = (int)__popcll(mlo) + __popc(mhi);
    int incl = nc;
    #pragma unroll
    for (int off = 1; off < 64; off <<= 1) {
        int u = __shfl_up(incl, off);
        if (lane >= off) incl += u;
    }
    int excl = incl - nc;
    int tot = __shfl(incl, 63);
    int base = 0;
    if (lane == 0 && tot > 0) base = atomicAdd(&cnt[n], tot);
    base = __shfl(base, 0);

    // ---- emit (p in registers; fully static indexing) ----
    if (nc > 0) {
        int pos = base + excl;
        uint2* cp = cand + (size_t)n * CAP;
        #pragma unroll
        for (int c = 1; c < NCLS; ++c) {
            bool bit = (c <= 64) ? (((mlo >> (c - 1)) & 1ull) != 0)
                                 : (((mhi >> (c - 65)) & 1u) != 0);
            if (bit) {
                if (pos < CAP) cp[pos] = make_uint2(__float_as_uint(e[c]),
                                                    (unsigned)(b * NC1 + (c - 1)));
                ++pos;
            }
        }
    }

    if (live && nc > 0) oboxes[(size_t)n * NBOX + b] = make_float4(l, tt, rr, bo);
}

// ============ LDS bitonic (descending), fallback path only ============
__device__ void bitonic_desc(unsigned long long* arr, int nn, int tid, int nt) {
    for (int k = 2; k <= nn; k <<= 1) {
        for (int j = k >> 1; j > 0; j >>= 1) {
            __syncthreads();
            for (int i = tid; i < nn; i += nt) {
                int ixj = i ^ j;
                if (ixj > i) {
                    unsigned long long a = arr[i], b = arr[ixj];
                    bool desc = ((i & k) == 0);
                    bool sw = desc ? (a < b) : (a > b);
                    if (sw) { arr[i] = b; arr[ixj] = a; }
                }
            }
        }
    }
    __syncthreads();
}

// ============ single-wave register bitonic sort (descending), N = 1<<LOGN ============
template<int LOGN>
__device__ __forceinline__ void wave_sort_desc(unsigned long long v[], int lane) {
    constexpr int NREG = (1 << LOGN) >> 6;
    #pragma unroll
    for (int kk = 1; kk <= LOGN; ++kk) {
        #pragma unroll
        for (int jj = kk - 1; jj >= 0; --jj) {
            if (jj >= 6) {
                const int jr = 1 << (jj - 6);
                #pragma unroll
                for (int r = 0; r < NREG; ++r) {
                    if ((r & jr) == 0) {
                        const int rp = r | jr;
                        const bool desc = (((r << 6) & (1 << kk)) == 0);
                        unsigned long long a = v[r], bq = v[rp];
                        bool sw = desc ? (a < bq) : (a > bq);
                        if (sw) { v[r] = bq; v[rp] = a; }
                    }
                }
            } else {
                const int j = 1 << jj;
                #pragma unroll
                for (int r = 0; r < NREG; ++r) {
                    unsigned long long a = v[r];
                    unsigned long long bq = __shfl_xor(a, j, 64);
                    bool isLow = ((lane & j) == 0);
                    bool desc = ((((r << 6) | lane) & (1 << kk)) == 0);
                    bool takeMax = (desc == isLow);
                    bool aGb = (a > bq);
                    v[r] = (takeMax == aGb) ? a : bq;
                }
            }
        }
    }
}

// ============ kernel 2: merged top-400 + IoU + NMS + top-100 + output ============
__global__ __launch_bounds__(1024) void k_select(const float4* __restrict__ boxes,
        const uint2* __restrict__ cand, const int* __restrict__ cnt,
        float* __restrict__ out) {
    __shared__ int hist[1024];
    __shared__ unsigned long long keys[COLCAP];   // also reused as final-sort output
    __shared__ float  s_score[TOPK];
    __shared__ float4 s_cbox[TOPK];
    __shared__ int    s_label[TOPK];
    __shared__ float4 s_ob[TOPK];
    __shared__ float  s_area[TOPK];
    __shared__ unsigned long long rows[TOPK * KW];
    __shared__ unsigned long long s_keep[KW];
    __shared__ int s_T, s_pos;

    int n = blockIdx.x;
    int tid = threadIdx.x;
    int lane = tid & 63;
    unsigned long long lmlt = (1ull << lane) - 1ull;
    int M = cnt[n]; if (M > CAP) M = CAP;
    const uint2* cp = cand + (size_t)n * CAP;

    hist[tid] = 0;
    if (tid == 0) s_pos = 0;
    __syncthreads();

    // ---- phase 1: histogram on top 16 bits of score ----
    for (int i = tid; i < M; i += 1024) {
        unsigned int bits = cp[i].x;
        int bk = (int)(bits >> 16) - 0x3D00;
        bk = max(0, min(1023, bk));
        atomicAdd(&hist[bk], 1);
    }
    __syncthreads();

    // ---- threshold T = max t with suffix-count >= TOPK (wave-0 parallel) ----
    if (tid < 64) {
        int sl = 0;
        #pragma unroll
        for (int t = 0; t < 16; ++t) sl += hist[tid * 16 + t];
        int incl = sl;
        #pragma unroll
        for (int off = 1; off < 64; off <<= 1) {
            int v = __shfl_down(incl, off);
            if (tid + off < 64) incl += v;
        }
        int xl = incl - sl;
        int tc = -1, cum = xl;
        for (int t = 15; t >= 0; --t) {
            cum += hist[tid * 16 + t];
            if (cum >= TOPK) { tc = tid * 16 + t; break; }
        }
        #pragma unroll
        for (int off = 32; off > 0; off >>= 1)
            tc = max(tc, __shfl_xor(tc, off));
        if (tid == 0) s_T = max(tc, 0);
    }
    __syncthreads();
    int T = s_T;

    // ---- phase 2: collect candidates >= threshold bucket (aggregated atomics) ----
    int iters = (M + 1023) / 1024;
    for (int it = 0; it < iters; ++it) {
        int i = it * 1024 + tid;
        bool pred = false; unsigned long long key = 0ull;
        if (i < M) {
            uint2 ee = cp[i];
            int bk = (int)(ee.x >> 16) - 0x3D00;
            bk = max(0, min(1023, bk));
            if (bk >= T) {
                pred = true;
                key = ((unsigned long long)ee.x << 32) | (unsigned int)(~ee.y);
            }
        }
        unsigned long long mask = __ballot(pred);
        int base = 0;
        if (lane == 0) {
            int cw = (int)__popcll(mask);
            if (cw) base = atomicAdd(&s_pos, cw);
        }
        base = __shfl(base, 0);
        if (pred) {
            int pos = base + (int)__popcll(mask & lmlt);
            if (pos < COLCAP) keys[pos] = key;
        }
    }
    __syncthreads();
    int ncol = min(s_pos, COLCAP);
    for (int i = ncol + tid; i < COLCAP; i += 1024) keys[i] = 0ull;
    __syncthreads();

    // ---- phase 3: sort (single-wave register bitonic; LDS fallback if huge) ----
    if (ncol <= 1024) {
        if (tid < 64) {
            unsigned long long v[16];
            #pragma unroll
            for (int r = 0; r < 16; ++r) v[r] = keys[(r << 6) | lane];
            wave_sort_desc<10>(v, lane);
            #pragma unroll
            for (int r = 0; r < 7; ++r) keys[(r << 6) | lane] = v[r];   // 448 >= TOPK
        }
    } else {
        bitonic_desc(keys, COLCAP, tid, 1024);
    }
    __syncthreads();

    // ---- phase 4: top-400 records into LDS ----
    int nsel = min(TOPK, ncol);
    if (tid < TOPK) {
        int i = tid;
        if (i < nsel) {
            unsigned long long key = keys[i];
            unsigned int bits = (unsigned int)(key >> 32);
            unsigned int flat = ~(unsigned int)key;
            int bb = (int)(flat / NC1);
            int lab = (int)(flat - (unsigned)bb * NC1) + 1;
            float sc = __uint_as_float(bits);
            float4 cb = boxes[(size_t)n * NBOX + bb];
            s_score[i] = sc; s_cbox[i] = cb; s_label[i] = lab;
            float off = 2.0f * (float)lab;
            float4 ob = make_float4(cb.x + off, cb.y + off, cb.z + off, cb.w + off);
            s_ob[i] = ob;
            s_area[i] = fmaxf(ob.z - ob.x, 0.f) * fmaxf(ob.w - ob.y, 0.f);
        } else {
            s_score[i] = -1.0f;
            s_cbox[i] = make_float4(0.f, 0.f, 0.f, 0.f);
            s_label[i] = 0;
            s_ob[i] = make_float4(0.f, 0.f, 0.f, 0.f);
            s_area[i] = 0.f;
        }
    }
    __syncthreads();

    // ---- phase 5: IoU suppression rows ----
    for (int t = tid; t < TOPK * KW; t += 1024) {
        int w = t / TOPK;
        int i = t - w * TOPK;
        unsigned long long cur = 0ull;
        if (i < nsel) {
            float4 oi = s_ob[i]; float ai = s_area[i];
            int j0 = w * 64;
            int jend = min(j0 + 64, nsel);
            for (int j = j0; j < jend; ++j) {
                if (j > i) {
                    float4 oj = s_ob[j];
                    float lx = fmaxf(oi.x, oj.x), ly = fmaxf(oi.y, oj.y);
                    float rx = fminf(oi.z, oj.z), ry = fminf(oi.w, oj.w);
                    float inter = fmaxf(rx - lx, 0.f) * fmaxf(ry - ly, 0.f);
                    float uni = fmaxf(ai + s_area[j] - inter, 1e-12f);
                    cur |= ((unsigned long long)(inter / uni > 0.5f)) << (j - j0);
                }
            }
        }
        rows[i * KW + w] = cur;
    }
    __syncthreads();

    // ---- phase 6: serial suppression, keep mask replicated in wave-0 registers ----
    if (tid < 64) {
        unsigned long long kp[KW];
        #pragma unroll
        for (int w = 0; w < KW; ++w) {
            int lo = w << 6;
            kp[w] = (nsel >= lo + 64) ? ~0ull
                  : (nsel <= lo ? 0ull : ((1ull << (nsel - lo)) - 1ull));
        }
        #pragma unroll
        for (int w = 0; w < KW; ++w) {
            int bitpos = 0;
            while (bitpos < 64) {
                unsigned long long mm = kp[w] & ((bitpos == 0) ? ~0ull : (~0ull << bitpos));
                if (!mm) break;
                int bq = (int)__ffsll((long long)mm) - 1;
                int i = (w << 6) + bq;       // kept index, in order -> suppress its row
                const unsigned long long* rp = &rows[i * KW];
                kp[0] &= ~rp[0]; kp[1] &= ~rp[1]; kp[2] &= ~rp[2]; kp[3] &= ~rp[3];
                kp[4] &= ~rp[4]; kp[5] &= ~rp[5]; kp[6] &= ~rp[6];
                bitpos = bq + 1;
            }
        }
        if (lane == 0) {
            #pragma unroll
            for (int w = 0; w < KW; ++w) s_keep[w] = kp[w];
        }
    }
    __syncthreads();

    // ---- phase 7: final stable top-100 via single-wave 512 register sort ----
    if (tid < 64) {
        unsigned long long v[8];
        #pragma unroll
        for (int r = 0; r < 8; ++r) {
            int i = (r << 6) | lane;
            unsigned long long key = 0ull;
            if (i < TOPK) {
                bool kb = (s_keep[i >> 6] >> (i & 63)) & 1ull;
                float fv = kb ? s_score[i] : -1.0f;
                key = ((unsigned long long)f2sort(fv) << 32) | (unsigned int)(~i);
            }
            v[r] = key;
        }
        wave_sort_desc<9>(v, lane);
        #pragma unroll
        for (int r = 0; r < 2; ++r) keys[(r << 6) | lane] = v[r];   // 128 >= MAXOUT
    }
    __syncthreads();

    float* obox = out;
    float* olab = out + (size_t)NIMG * MAXOUT * 4;
    float* osco = out + (size_t)NIMG * MAXOUT * 5;
    if (tid < MAXOUT) {
        int k = tid;
        unsigned long long key = keys[k];
        int slot = (int)(~(unsigned int)key);
        float4 cb = make_float4(0.f, 0.f, 0.f, 0.f);
        float lab = 0.f, sv = 0.f;
        if (slot >= 0 && slot < TOPK) {
            bool kb = (s_keep[slot >> 6] >> (slot & 63)) & 1ull;
            float fv = kb ? s_score[slot] : -1.0f;
            if (fv > 0.0f) {
                cb = s_cbox[slot];
                lab = (float)s_label[slot];
                sv = fv;
            }
        }
        size_t bo_ = ((size_t)n * MAXOUT + k) * 4;
        obox[bo_ + 0] = cb.x; obox[bo_ + 1] = cb.y; obox[bo_ + 2] = cb.z; obox[bo_ + 3] = cb.w;
        olab[(size_t)n * MAXOUT + k] = lab;
        osco[(size_t)n * MAXOUT + k] = sv;
    }
}

extern "C" void kernel_launch(void* const* d_in, const int* in_sizes, int n_in,
                              void* d_out, int out_size, void* d_ws, size_t ws_size,
                              hipStream_t stream) {
    (void)in_sizes; (void)n_in; (void)out_size; (void)ws_size;
    const float* bboxes = (const float*)d_in[0];
    const float* scores = (const float*)d_in[1];
    const float* dbox   = (const float*)d_in[2];
    float* out = (float*)d_out;

    char* ws = (char*)d_ws;
    size_t off = 0;
    float4* oboxes = (float4*)(ws + off); off += (size_t)NIMG * NBOX * sizeof(float4);
    int* cnt = (int*)(ws + off); off += 256;
    uint2* cand = (uint2*)(ws + off); off += (size_t)NIMG * CAP * sizeof(uint2);

    hipMemsetAsync(cnt, 0, NIMG * sizeof(int), stream);

    int gx = (NBOX + BDEC - 1) / BDEC;   // 35
    k_decode<<<dim3(gx, NIMG), BDEC, 0, stream>>>(bboxes, scores, dbox, oboxes, cand, cnt);
    k_select<<<NIMG, 1024, 0, stream>>>(oboxes, cand, cnt, out);
}